// Round 13
// baseline (237.508 us; speedup 1.0000x reference)
//
#include <hip/hip_runtime.h>

// Problem constants
#define NB 16
#define NC 64
#define NM 6
#define ND 192
#define NHEADS 8
#define NCH 64
#define NINNER 512
#define PLANE 6144             // 64*96 floats per (b,c) plane
#define XB (NC*PLANE)          // 393216 floats of x per batch
#define NKEY 768               // unique keys per head (dup-8 collapses in softmax)
#define NCHUNK 8
#define CK 96                  // keys per chunk (8*96 = 768)

// ============================================================================
// Kernel 1: pool (all 1024 blocks) + zq tail (last block per batch).
// Last-arriver: NO polling — the block that draws ticket 63 for its batch
// continues into the zq work for that batch (~1.3M MAC, ~2us, 16 concurrent).
// Visibility across XCDs: all-thread __threadfence (device-scope writeback)
// -> __syncthreads -> tid0 device-scope atomicAdd; consumer cold-reads hit L3.
// ============================================================================
__global__ __launch_bounds__(256) void pool_zq_kernel(
    const float* __restrict__ x, const float* __restrict__ z,
    const float* __restrict__ conv_w, const float* __restrict__ conv_b,
    const float* __restrict__ wq, const float* __restrict__ bq,
    float* __restrict__ xmean, float* __restrict__ znew,
    float* __restrict__ qr, unsigned* __restrict__ cnt)
{
    int bc = blockIdx.x, b = bc >> 6;
    int tid = threadIdx.x;
    __shared__ float part[4][6];
    __shared__ float xm_s[NC * NM];          // [c][m]
    __shared__ float zn_s[NM * ND];          // [m][d]
    __shared__ bool lastf;

    // ---- pool body (verbatim R10) ----
    {
        const float4* p = (const float4*)(x + (size_t)bc * PLANE);
        float acc[6] = {0.f,0.f,0.f,0.f,0.f,0.f};
        #pragma unroll
        for (int k = 0; k < 6; ++k) {
            int idx4 = tid + k * 256;
            int hh = idx4 / 24;
            int w4 = idx4 - hh * 24;
            int j = (hh >> 5) * 3 + (w4 >> 3);
            float4 v = p[idx4];
            acc[j] += v.x + v.y + v.z + v.w;
        }
        int lane = tid & 63, wave = tid >> 6;
        #pragma unroll
        for (int j = 0; j < 6; ++j) {
            float v = acc[j];
            for (int off = 32; off > 0; off >>= 1) v += __shfl_down(v, off, 64);
            acc[j] = v;
        }
        if (lane == 0) {
            #pragma unroll
            for (int j = 0; j < 6; ++j) part[wave][j] = acc[j];
        }
        __syncthreads();
        if (tid < 6) {
            float s = part[0][tid] + part[1][tid] + part[2][tid] + part[3][tid];
            xmean[bc * 6 + tid] = s * (1.0f / 1024.0f);
        }
    }

    // ---- last-arriver handoff ----
    __threadfence();
    __syncthreads();
    if (tid == 0) lastf = (atomicAdd(&cnt[b * 16], 1u) == 63);
    __syncthreads();
    if (!lastf) return;
    __threadfence();

    // ---- zq tail for batch b ----
    for (int i = tid; i < NC * NM; i += 256) xm_s[i] = xmean[b * 384 + i];
    __syncthreads();
    for (int i = tid; i < NM * ND; i += 256) {
        int m = i / ND, d = i - m * ND;
        float a = conv_b[d];
        const float4* wr4 = (const float4*)(conv_w + d * NC);
        #pragma unroll
        for (int c4 = 0; c4 < 16; ++c4) {
            float4 w = wr4[c4];
            a += w.x * xm_s[(c4 * 4 + 0) * 6 + m] + w.y * xm_s[(c4 * 4 + 1) * 6 + m]
               + w.z * xm_s[(c4 * 4 + 2) * 6 + m] + w.w * xm_s[(c4 * 4 + 3) * 6 + m];
        }
        float v = z[b * 1152 + i] + a;
        zn_s[i] = v;
        znew[b * 1152 + i] = v;
    }
    __syncthreads();
    // q: thread owns wq cols {2*tid, 2*tid+1}; float2 loads; verified remap
    // qr[b][t=m*8+(col>>6)][col&63].
    {
        int c0 = tid * 2;
        float2 acc[NM];
        #pragma unroll
        for (int m = 0; m < NM; ++m) acc[m] = make_float2(0.f, 0.f);
        #pragma unroll 4
        for (int d = 0; d < ND; ++d) {
            float2 w = *(const float2*)&wq[d * NINNER + c0];
            #pragma unroll
            for (int m = 0; m < NM; ++m) {
                float zv = zn_s[m * ND + d];
                acc[m].x += zv * w.x;
                acc[m].y += zv * w.y;
            }
        }
        float bq0 = bq[c0], bq1 = bq[c0 + 1];
        int cg = c0 >> 6, cl = c0 & 63;      // c0+1 shares cg; cl+1 = (c0+1)&63
        #pragma unroll
        for (int m = 0; m < NM; ++m) {
            float* dst = qr + b * 3072 + (m * 8 + cg) * 64 + cl;
            dst[0] = acc[m].x + bq0;
            dst[1] = acc[m].y + bq1;
        }
    }
}

// ============================================================================
// Kernel 2: fattn v5 (all 1024 blocks, 5 blocks/CU) + proj tail (last block
// per batch): den[48] + orow[6][512] built in LDS (aliasing k_lds), then
// wo-GEMM with coalesced wo rows and broadcast LDS reads.
// ============================================================================
__global__ __launch_bounds__(256, 5) void fattn_proj_kernel(
    const float* __restrict__ x, const float* __restrict__ qr,
    const float* __restrict__ wo, const float* __restrict__ bo,
    const float* __restrict__ znew,
    float* __restrict__ po, float* __restrict__ ps,
    unsigned* __restrict__ cnt, float* __restrict__ out)
{
    int blk = blockIdx.x;                    // ((b*8+head)*8+chunk)
    int chunk = blk & 7, bh = blk >> 3;
    int head = bh & 7, b = bh >> 3;
    int tid = threadIdx.x;
    __shared__ float k_lds[CK][NCH];         // 24576 B (tail aliases this)
    __shared__ float q_lds[NM][NCH];         //  1536 B
    __shared__ float s_lds[NM][CK];          //  2304 B   (total 28416 B)
    __shared__ bool lastf;
    const float* kbase = x + (size_t)b * XB + (size_t)(head * NKEY + chunk * CK) * NCH;

    // q load (coalesced; qr pre-permuted)
    for (int i = tid; i < NM * NCH; i += 256) {
        int mi = i >> 6, ch = i & 63;
        q_lds[mi][ch] = qr[b * (48 * 64) + (head * NM + mi) * 64 + ch];
    }
    // k tile: 96 rows x 16 float4
    const float4* k4 = (const float4*)kbase;
    #pragma unroll
    for (int r = 0; r < 6; ++r) {
        int i = tid + r * 256;
        int row = i >> 4, c4 = i & 15;
        float4 v = k4[i];
        *(float4*)&k_lds[row][c4 * 4] = v;
    }
    __syncthreads();

    // dots + exp: 96 threads, thread = k-row u, all 6 m; rotated c4
    if (tid < 96) {
        int u = tid;
        float a[NM] = {0.f,0.f,0.f,0.f,0.f,0.f};
        #pragma unroll
        for (int c4 = 0; c4 < 16; ++c4) {
            int cc = ((c4 + u) & 15) * 4;
            float4 kv = *(const float4*)&k_lds[u][cc];
            #pragma unroll
            for (int mo = 0; mo < NM; ++mo) {
                float4 qv = *(const float4*)&q_lds[mo][cc];
                a[mo] += kv.x*qv.x + kv.y*qv.y + kv.z*qv.z + kv.w*qv.w;
            }
        }
        #pragma unroll
        for (int mo = 0; mo < NM; ++mo) s_lds[mo][u] = __expf(a[mo] * 0.125f);
    }
    __syncthreads();

    int lane = tid & 63, wave = tid >> 6;
    if (wave < 2) {
        // PV: thread (ch, trio) walks all 96 rows; direct po write
        int ch = lane, m0 = wave * 3;
        float a0 = 0.f, a1 = 0.f, a2 = 0.f;
        #pragma unroll
        for (int u0 = 0; u0 < CK; u0 += 4) {
            float4 s0 = *(const float4*)&s_lds[m0 + 0][u0];
            float4 s1 = *(const float4*)&s_lds[m0 + 1][u0];
            float4 s2 = *(const float4*)&s_lds[m0 + 2][u0];
            float kv0 = k_lds[u0 + 0][ch];
            float kv1 = k_lds[u0 + 1][ch];
            float kv2 = k_lds[u0 + 2][ch];
            float kv3 = k_lds[u0 + 3][ch];
            a0 += s0.x*kv0 + s0.y*kv1 + s0.z*kv2 + s0.w*kv3;
            a1 += s1.x*kv0 + s1.y*kv1 + s1.z*kv2 + s1.w*kv3;
            a2 += s2.x*kv0 + s2.y*kv1 + s2.z*kv2 + s2.w*kv3;
        }
        float* pob = po + (size_t)blk * (NM * NCH);
        pob[(m0 + 0) * NCH + ch] = a0;
        pob[(m0 + 1) * NCH + ch] = a1;
        pob[(m0 + 2) * NCH + ch] = a2;
    } else {
        // denominators: waves 2-3, 6 rows in 3 rounds
        #pragma unroll
        for (int rnd = 0; rnd < 3; ++rnd) {
            int mi = rnd * 2 + (wave - 2);
            float v = s_lds[mi][lane] + ((lane < 32) ? s_lds[mi][64 + lane] : 0.f);
            for (int msk = 1; msk < 64; msk <<= 1) v += __shfl_xor(v, msk, 64);
            if (lane == 0) ps[blk * NM + mi] = v;
        }
    }

    // ---- last-arriver handoff ----
    __threadfence();
    __syncthreads();
    if (tid == 0) lastf = (atomicAdd(&cnt[b * 16], 1u) == 63);
    __syncthreads();
    if (!lastf) return;
    __threadfence();

    // ---- proj tail for batch b (aliases k_lds) ----
    float* orow  = &k_lds[0][0];             // 3072 floats
    float* den_l = orow + 3072;              // 48 floats (fits: k_lds = 6144)
    if (tid < 48) {                          // tid = h*6+m
        int h = tid / 6, m = tid - h * 6;
        int base = (b * NHEADS + h) * NCHUNK;
        float s = 0.f;
        #pragma unroll
        for (int c = 0; c < NCHUNK; ++c) s += ps[(base + c) * NM + m];
        den_l[tid] = s;
    }
    __syncthreads();
    for (int i = tid; i < NM * NINNER; i += 256) {
        int m = i >> 9, col = i & 511, h = col >> 6, ch = col & 63;
        int base = (b * NHEADS + h) * NCHUNK;
        float num = 0.f;
        #pragma unroll
        for (int c = 0; c < NCHUNK; ++c)
            num += po[(size_t)(base + c) * (NM * NCH) + m * NCH + ch];
        orow[i] = num / den_l[h * 6 + m];
    }
    __syncthreads();
    if (tid < ND) {                          // col2 = tid; wo rows coalesced
        float acc[NM] = {0.f,0.f,0.f,0.f,0.f,0.f};
        #pragma unroll 2
        for (int i4 = 0; i4 < NINNER; i4 += 4) {
            float w0 = wo[(i4 + 0) * ND + tid];
            float w1 = wo[(i4 + 1) * ND + tid];
            float w2 = wo[(i4 + 2) * ND + tid];
            float w3 = wo[(i4 + 3) * ND + tid];
            #pragma unroll
            for (int m = 0; m < NM; ++m) {
                float4 sv = *(const float4*)&orow[m * NINNER + i4];
                acc[m] += sv.x*w0 + sv.y*w1 + sv.z*w2 + sv.w*w3;
            }
        }
        float bov = bo[tid];
        #pragma unroll
        for (int m = 0; m < NM; ++m)
            out[(b * NM + m) * ND + tid] = acc[m] + bov
                                         + znew[b * 1152 + m * ND + tid];
    }
}

extern "C" void kernel_launch(void* const* d_in, const int* in_sizes, int n_in,
                              void* d_out, int out_size, void* d_ws, size_t ws_size,
                              hipStream_t stream) {
    const float* x      = (const float*)d_in[0];
    const float* z      = (const float*)d_in[1];
    const float* conv_w = (const float*)d_in[2];
    const float* conv_b = (const float*)d_in[3];
    const float* wq     = (const float*)d_in[4];
    const float* bq     = (const float*)d_in[5];
    const float* wo     = (const float*)d_in[6];
    const float* bo     = (const float*)d_in[7];
    float* out = (float*)d_out;

    float* ws    = (float*)d_ws;
    float* xmean = ws;              // 16*64*6          = 6144
    float* znew  = ws + 6144;       // 16*6*192         = 18432
    float* qr    = ws + 24576;      // 16*48*64         = 49152
    float* po    = ws + 73728;      // 1024*6*64        = 393216
    float* ps    = ws + 466944;     // 1024*6           = 6144
    unsigned* cnt = (unsigned*)(ws + 473088);   // 2 x [16] stride-16 = 2KB

    hipMemsetAsync((void*)cnt, 0, 512 * sizeof(unsigned), stream);

    pool_zq_kernel<<<NB*NC, 256, 0, stream>>>(x, z, conv_w, conv_b, wq, bq,
                                              xmean, znew, qr, cnt);
    fattn_proj_kernel<<<NB*NHEADS*NCHUNK, 256, 0, stream>>>(x, qr, wo, bo, znew,
                                                            po, ps, cnt + 256, out);
}

// Round 14
// 97.577 us; speedup vs baseline: 2.4341x; 2.4341x over previous
//
#include <hip/hip_runtime.h>

// Problem constants
#define NB 16
#define NC 64
#define NM 6
#define ND 192
#define NHEADS 8
#define NCH 64
#define NINNER 512
#define PLANE 6144             // 64*96 floats per (b,c) plane
#define XB (NC*PLANE)          // 393216 floats of x per batch
#define NKEY 768               // unique keys per head (dup-8 collapses in softmax)
#define NCHUNK 8
#define CK 96                  // keys per chunk (8*96 = 768)

// Relaxed agent-scope atomic access: data moves via the device coherence
// point (L3) — bypasses the non-coherent per-XCD L2s WITHOUT any fence.
__device__ __forceinline__ void ast(float* p, float v) {
    __hip_atomic_store(p, v, __ATOMIC_RELAXED, __HIP_MEMORY_SCOPE_AGENT);
}
__device__ __forceinline__ float ald(const float* p) {
    return __hip_atomic_load(p, __ATOMIC_RELAXED, __HIP_MEMORY_SCOPE_AGENT);
}

// ============================================================================
// Kernel 1: pool (1024 blocks) + zq tail (last-arriver per batch).
// NO fences: xmean via relaxed atomic stores/loads (coherent at L3);
// per-wave s_waitcnt vmcnt(0) (own-stores drained, ~100cy, NOT a cache flush)
// before the ticket. Ticket 63 => all 64 blocks' xmean is at L3.
// ============================================================================
__global__ __launch_bounds__(256) void pool_zq_kernel(
    const float* __restrict__ x, const float* __restrict__ z,
    const float* __restrict__ conv_w, const float* __restrict__ conv_b,
    const float* __restrict__ wq, const float* __restrict__ bq,
    float* __restrict__ xmean, float* __restrict__ znew,
    float* __restrict__ qr, unsigned* __restrict__ cnt)
{
    int bc = blockIdx.x, b = bc >> 6;
    int tid = threadIdx.x;
    __shared__ float part[4][6];
    __shared__ float xm_s[NC * NM];          // [c][m]
    __shared__ float zn_s[NM * ND];          // [m][d]
    __shared__ bool lastf;

    // ---- pool body (verbatim R10) ----
    {
        const float4* p = (const float4*)(x + (size_t)bc * PLANE);
        float acc[6] = {0.f,0.f,0.f,0.f,0.f,0.f};
        #pragma unroll
        for (int k = 0; k < 6; ++k) {
            int idx4 = tid + k * 256;
            int hh = idx4 / 24;
            int w4 = idx4 - hh * 24;
            int j = (hh >> 5) * 3 + (w4 >> 3);
            float4 v = p[idx4];
            acc[j] += v.x + v.y + v.z + v.w;
        }
        int lane = tid & 63, wave = tid >> 6;
        #pragma unroll
        for (int j = 0; j < 6; ++j) {
            float v = acc[j];
            for (int off = 32; off > 0; off >>= 1) v += __shfl_down(v, off, 64);
            acc[j] = v;
        }
        if (lane == 0) {
            #pragma unroll
            for (int j = 0; j < 6; ++j) part[wave][j] = acc[j];
        }
        __syncthreads();
        if (tid < 6) {
            float s = part[0][tid] + part[1][tid] + part[2][tid] + part[3][tid];
            ast(&xmean[bc * 6 + tid], s * (1.0f / 1024.0f));
        }
    }

    // ---- fence-free last-arriver handoff ----
    asm volatile("s_waitcnt vmcnt(0)" ::: "memory");   // own stores at L3
    __syncthreads();
    if (tid == 0)
        lastf = (__hip_atomic_fetch_add(&cnt[b * 16], 1u, __ATOMIC_RELAXED,
                                        __HIP_MEMORY_SCOPE_AGENT) == 63);
    __syncthreads();
    if (!lastf) return;

    // ---- zq tail for batch b (R13-verified logic; xmean via atomic loads) --
    for (int i = tid; i < NC * NM; i += 256) xm_s[i] = ald(&xmean[b * 384 + i]);
    __syncthreads();
    for (int i = tid; i < NM * ND; i += 256) {
        int m = i / ND, d = i - m * ND;
        float a = conv_b[d];
        const float4* wr4 = (const float4*)(conv_w + d * NC);
        #pragma unroll
        for (int c4 = 0; c4 < 16; ++c4) {
            float4 w = wr4[c4];
            a += w.x * xm_s[(c4 * 4 + 0) * 6 + m] + w.y * xm_s[(c4 * 4 + 1) * 6 + m]
               + w.z * xm_s[(c4 * 4 + 2) * 6 + m] + w.w * xm_s[(c4 * 4 + 3) * 6 + m];
        }
        float v = z[b * 1152 + i] + a;
        zn_s[i] = v;
        znew[b * 1152 + i] = v;              // cross-kernel: normal store OK
    }
    __syncthreads();
    // q: thread owns wq cols {2*tid, 2*tid+1}; qr[b][t=m*8+(col>>6)][col&63]
    {
        int c0 = tid * 2;
        float2 acc[NM];
        #pragma unroll
        for (int m = 0; m < NM; ++m) acc[m] = make_float2(0.f, 0.f);
        #pragma unroll 4
        for (int d = 0; d < ND; ++d) {
            float2 w = *(const float2*)&wq[d * NINNER + c0];
            #pragma unroll
            for (int m = 0; m < NM; ++m) {
                float zv = zn_s[m * ND + d];
                acc[m].x += zv * w.x;
                acc[m].y += zv * w.y;
            }
        }
        float bq0 = bq[c0], bq1 = bq[c0 + 1];
        int cg = c0 >> 6, cl = c0 & 63;
        #pragma unroll
        for (int m = 0; m < NM; ++m) {
            float* dst = qr + b * 3072 + (m * 8 + cg) * 64 + cl;
            dst[0] = acc[m].x + bq0;         // cross-kernel: normal store OK
            dst[1] = acc[m].y + bq1;
        }
    }
}

// ============================================================================
// Kernel 2: fattn v5 (1024 blocks, 5 blocks/CU) + proj tail (last-arriver
// per batch). po/ps via relaxed atomics; same fence-free handoff.
// ============================================================================
__global__ __launch_bounds__(256, 5) void fattn_proj_kernel(
    const float* __restrict__ x, const float* __restrict__ qr,
    const float* __restrict__ wo, const float* __restrict__ bo,
    const float* __restrict__ znew,
    float* __restrict__ po, float* __restrict__ ps,
    unsigned* __restrict__ cnt, float* __restrict__ out)
{
    int blk = blockIdx.x;                    // ((b*8+head)*8+chunk)
    int chunk = blk & 7, bh = blk >> 3;
    int head = bh & 7, b = bh >> 3;
    int tid = threadIdx.x;
    __shared__ float k_lds[CK][NCH];         // 24576 B (tail aliases this)
    __shared__ float q_lds[NM][NCH];         //  1536 B
    __shared__ float s_lds[NM][CK];          //  2304 B
    __shared__ bool lastf;
    const float* kbase = x + (size_t)b * XB + (size_t)(head * NKEY + chunk * CK) * NCH;

    // q load (qr from kernel 1 — cross-kernel, normal loads)
    for (int i = tid; i < NM * NCH; i += 256) {
        int mi = i >> 6, ch = i & 63;
        q_lds[mi][ch] = qr[b * (48 * 64) + (head * NM + mi) * 64 + ch];
    }
    // k tile: 96 rows x 16 float4
    const float4* k4 = (const float4*)kbase;
    #pragma unroll
    for (int r = 0; r < 6; ++r) {
        int i = tid + r * 256;
        int row = i >> 4, c4 = i & 15;
        float4 v = k4[i];
        *(float4*)&k_lds[row][c4 * 4] = v;
    }
    __syncthreads();

    // dots + exp: 96 threads, thread = k-row u, all 6 m; rotated c4
    if (tid < 96) {
        int u = tid;
        float a[NM] = {0.f,0.f,0.f,0.f,0.f,0.f};
        #pragma unroll
        for (int c4 = 0; c4 < 16; ++c4) {
            int cc = ((c4 + u) & 15) * 4;
            float4 kv = *(const float4*)&k_lds[u][cc];
            #pragma unroll
            for (int mo = 0; mo < NM; ++mo) {
                float4 qv = *(const float4*)&q_lds[mo][cc];
                a[mo] += kv.x*qv.x + kv.y*qv.y + kv.z*qv.z + kv.w*qv.w;
            }
        }
        #pragma unroll
        for (int mo = 0; mo < NM; ++mo) s_lds[mo][u] = __expf(a[mo] * 0.125f);
    }
    __syncthreads();

    int lane = tid & 63, wave = tid >> 6;
    if (wave < 2) {
        // PV: thread (ch, trio) walks all 96 rows; po via atomic stores
        int ch = lane, m0 = wave * 3;
        float a0 = 0.f, a1 = 0.f, a2 = 0.f;
        #pragma unroll
        for (int u0 = 0; u0 < CK; u0 += 4) {
            float4 s0 = *(const float4*)&s_lds[m0 + 0][u0];
            float4 s1 = *(const float4*)&s_lds[m0 + 1][u0];
            float4 s2 = *(const float4*)&s_lds[m0 + 2][u0];
            float kv0 = k_lds[u0 + 0][ch];
            float kv1 = k_lds[u0 + 1][ch];
            float kv2 = k_lds[u0 + 2][ch];
            float kv3 = k_lds[u0 + 3][ch];
            a0 += s0.x*kv0 + s0.y*kv1 + s0.z*kv2 + s0.w*kv3;
            a1 += s1.x*kv0 + s1.y*kv1 + s1.z*kv2 + s1.w*kv3;
            a2 += s2.x*kv0 + s2.y*kv1 + s2.z*kv2 + s2.w*kv3;
        }
        float* pob = po + (size_t)blk * (NM * NCH);
        ast(&pob[(m0 + 0) * NCH + ch], a0);
        ast(&pob[(m0 + 1) * NCH + ch], a1);
        ast(&pob[(m0 + 2) * NCH + ch], a2);
    } else {
        // denominators: waves 2-3, 6 rows in 3 rounds; ps via atomic stores
        #pragma unroll
        for (int rnd = 0; rnd < 3; ++rnd) {
            int mi = rnd * 2 + (wave - 2);
            float v = s_lds[mi][lane] + ((lane < 32) ? s_lds[mi][64 + lane] : 0.f);
            for (int msk = 1; msk < 64; msk <<= 1) v += __shfl_xor(v, msk, 64);
            if (lane == 0) ast(&ps[blk * NM + mi], v);
        }
    }

    // ---- fence-free last-arriver handoff ----
    asm volatile("s_waitcnt vmcnt(0)" ::: "memory");   // own stores at L3
    __syncthreads();
    if (tid == 0)
        lastf = (__hip_atomic_fetch_add(&cnt[b * 16], 1u, __ATOMIC_RELAXED,
                                        __HIP_MEMORY_SCOPE_AGENT) == 63);
    __syncthreads();
    if (!lastf) return;

    // ---- proj tail for batch b (aliases k_lds; po/ps via atomic loads) ----
    float* orow  = &k_lds[0][0];             // 3072 floats
    float* den_l = orow + 3072;              // 48 floats
    if (tid < 48) {                          // tid = h*6+m
        int h = tid / 6, m = tid - h * 6;
        int base = (b * NHEADS + h) * NCHUNK;
        float s = 0.f;
        #pragma unroll
        for (int c = 0; c < NCHUNK; ++c) s += ald(&ps[(base + c) * NM + m]);
        den_l[tid] = s;
    }
    __syncthreads();
    for (int i = tid; i < NM * NINNER; i += 256) {
        int m = i >> 9, col = i & 511, h = col >> 6, ch = col & 63;
        int base = (b * NHEADS + h) * NCHUNK;
        float num = 0.f;
        #pragma unroll
        for (int c = 0; c < NCHUNK; ++c)
            num += ald(&po[(size_t)(base + c) * (NM * NCH) + m * NCH + ch]);
        orow[i] = num / den_l[h * 6 + m];
    }
    __syncthreads();
    if (tid < ND) {                          // wo rows coalesced; out normal
        float acc[NM] = {0.f,0.f,0.f,0.f,0.f,0.f};
        #pragma unroll 2
        for (int i4 = 0; i4 < NINNER; i4 += 4) {
            float w0 = wo[(i4 + 0) * ND + tid];
            float w1 = wo[(i4 + 1) * ND + tid];
            float w2 = wo[(i4 + 2) * ND + tid];
            float w3 = wo[(i4 + 3) * ND + tid];
            #pragma unroll
            for (int m = 0; m < NM; ++m) {
                float4 sv = *(const float4*)&orow[m * NINNER + i4];
                acc[m] += sv.x*w0 + sv.y*w1 + sv.z*w2 + sv.w*w3;
            }
        }
        float bov = bo[tid];
        #pragma unroll
        for (int m = 0; m < NM; ++m)
            out[(b * NM + m) * ND + tid] = acc[m] + bov
                                         + znew[b * 1152 + m * ND + tid];
    }
}

extern "C" void kernel_launch(void* const* d_in, const int* in_sizes, int n_in,
                              void* d_out, int out_size, void* d_ws, size_t ws_size,
                              hipStream_t stream) {
    const float* x      = (const float*)d_in[0];
    const float* z      = (const float*)d_in[1];
    const float* conv_w = (const float*)d_in[2];
    const float* conv_b = (const float*)d_in[3];
    const float* wq     = (const float*)d_in[4];
    const float* bq     = (const float*)d_in[5];
    const float* wo     = (const float*)d_in[6];
    const float* bo     = (const float*)d_in[7];
    float* out = (float*)d_out;

    float* ws    = (float*)d_ws;
    float* xmean = ws;              // 16*64*6          = 6144
    float* znew  = ws + 6144;       // 16*6*192         = 18432
    float* qr    = ws + 24576;      // 16*48*64         = 49152
    float* po    = ws + 73728;      // 1024*6*64        = 393216
    float* ps    = ws + 466944;     // 1024*6           = 6144
    unsigned* cnt = (unsigned*)(ws + 473088);   // 2 x [16] stride-16 = 2KB

    hipMemsetAsync((void*)cnt, 0, 512 * sizeof(unsigned), stream);

    pool_zq_kernel<<<NB*NC, 256, 0, stream>>>(x, z, conv_w, conv_b, wq, bq,
                                              xmean, znew, qr, cnt);
    fattn_proj_kernel<<<NB*NHEADS*NCHUNK, 256, 0, stream>>>(x, qr, wo, bo, znew,
                                                            po, ps, cnt + 256, out);
}

// Round 15
// 44.840 us; speedup vs baseline: 5.2968x; 2.1761x over previous
//
#include <hip/hip_runtime.h>

// Problem constants
#define NB 16
#define NC 64
#define NM 6
#define ND 192
#define NHEADS 8
#define NCH 64
#define NINNER 512
#define PLANE 6144             // 64*96 floats per (b,c) plane
#define XB (NC*PLANE)          // 393216 floats of x per batch
#define NKEY 768               // unique keys per head (dup-8 collapses in softmax)
#define NCHUNK 8
#define CK 96                  // keys per chunk (8*96 = 768)

// ============================================================================
// Kernel 1: three independent roles, one dispatch (no inter-block deps):
//   bid <  1024 : pool   — xmean[b,c,:] (verbatim R10 body)
//   bid <  1792 : qz     — qz[blk*64+colL] = bq + (z+conv_b)·wq  (z-only!)
//   bid >= 1792 : CW     — cwt[col][c] = sum_d conv_w[d][c]*wq[d][col]
// q = qz + xmean·CW is completed inside fattn (64 MAC/elem, CW L2-resident).
// ============================================================================
__global__ __launch_bounds__(256) void k1_kernel(
    const float* __restrict__ x, const float* __restrict__ z,
    const float* __restrict__ conv_w, const float* __restrict__ conv_b,
    const float* __restrict__ wq, const float* __restrict__ bq,
    float* __restrict__ xmean, float* __restrict__ qz,
    float* __restrict__ cwt)
{
    int bid = blockIdx.x;
    int tid = threadIdx.x;
    __shared__ float sh[448];

    if (bid < 1024) {
        // ---- pool (bc = bid), verbatim R10 ----
        int bc = bid;
        const float4* p = (const float4*)(x + (size_t)bc * PLANE);
        float acc[6] = {0.f,0.f,0.f,0.f,0.f,0.f};
        #pragma unroll
        for (int k = 0; k < 6; ++k) {
            int idx4 = tid + k * 256;
            int hh = idx4 / 24;
            int w4 = idx4 - hh * 24;
            int j = (hh >> 5) * 3 + (w4 >> 3);
            float4 v = p[idx4];
            acc[j] += v.x + v.y + v.z + v.w;
        }
        int lane = tid & 63, wave = tid >> 6;
        #pragma unroll
        for (int j = 0; j < 6; ++j) {
            float v = acc[j];
            for (int off = 32; off > 0; off >>= 1) v += __shfl_down(v, off, 64);
            acc[j] = v;
        }
        float* part = sh;                    // [4][6]
        if (lane == 0) {
            #pragma unroll
            for (int j = 0; j < 6; ++j) part[wave * 6 + j] = acc[j];
        }
        __syncthreads();
        if (tid < 6) {
            float s = part[tid] + part[6 + tid] + part[12 + tid] + part[18 + tid];
            xmean[bc * 6 + tid] = s * (1.0f / 1024.0f);
        }
    } else if (bid < 1792) {
        // ---- qz (blk = bid-1024): old zq minus the conv/xmean term ----
        int blk = bid - 1024;
        int cgrp = blk & 7, bm = blk >> 3;   // bm = b*6+m
        float* zc    = sh;                   // 192
        float* qpart = sh + 192;             // 3*64
        if (tid < ND) zc[tid] = z[bm * ND + tid] + conv_b[tid];
        __syncthreads();
        int colL = tid & 63, ks = tid >> 6;  // 64 cols x 4-way split-K(48)
        int col = cgrp * 64 + colL;
        float a = (ks == 0) ? bq[col] : 0.f;
        int d0 = ks * 48;
        #pragma unroll
        for (int d = d0; d < d0 + 48; ++d) a += zc[d] * wq[d * NINNER + col];
        if (ks > 0) qpart[(ks - 1) * 64 + colL] = a;
        __syncthreads();
        if (ks == 0) {
            // addr identity: (bm*8+cgrp)*64+colL == blk*64+colL (verified layout)
            qz[blk * 64 + colL] = a + qpart[colL] + qpart[64 + colL] + qpart[128 + colL];
        }
    } else {
        // ---- CW (j = bid-1792): cols j*8..j*8+7; 2 elems/thread (same c) ----
        int j = bid - 1792;
        int c = tid & 63, cl0 = tid >> 6;    // elems (cl0, cl0+4)
        float a0 = 0.f, a1 = 0.f;
        const float* wc = conv_w + c;        // conv_w[d][c] stride 64
        const float* w0 = wq + j * 8 + cl0;
        const float* w1 = w0 + 4;
        #pragma unroll 8
        for (int d = 0; d < ND; ++d) {
            float cwv = wc[d * NC];
            a0 += cwv * w0[d * NINNER];
            a1 += cwv * w1[d * NINNER];
        }
        cwt[(j * 8 + cl0    ) * 64 + c] = a0;
        cwt[(j * 8 + cl0 + 4) * 64 + c] = a1;
    }
}

// ============================================================================
// Kernel 2: fattn v5 + in-block q completion (q = qz + xmT·CW).
// grid 1024, 256 thr, LDS 29952B -> 5 blocks/CU.
// ============================================================================
__global__ __launch_bounds__(256, 5) void fattn_kernel(
    const float* __restrict__ x, const float* __restrict__ qz,
    const float* __restrict__ cwt, const float* __restrict__ xmean,
    float* __restrict__ po, float* __restrict__ ps)
{
    int blk = blockIdx.x;                    // ((b*8+head)*8+chunk)
    int chunk = blk & 7, bh = blk >> 3;
    int head = bh & 7, b = bh >> 3;
    int tid = threadIdx.x;
    __shared__ float k_lds[CK][NCH];         // 24576 B
    __shared__ float q_lds[NM][NCH];         //  1536 B
    __shared__ float s_lds[NM][CK];          //  2304 B
    __shared__ float xmT[NM][NC];            //  1536 B  (total 29952 B)
    const float* kbase = x + (size_t)b * XB + (size_t)(head * NKEY + chunk * CK) * NCH;

    // stage xmT[m][c] = xmean[b*384 + c*6 + m]
    for (int i = tid; i < NC * NM; i += 256) {
        int c = i / 6, m = i - c * 6;
        xmT[m][c] = xmean[b * 384 + i];
    }
    // stage k: 96 rows x 16 float4
    const float4* k4 = (const float4*)kbase;
    #pragma unroll
    for (int r = 0; r < 6; ++r) {
        int i = tid + r * 256;
        int row = i >> 4, c4 = i & 15;
        float4 v = k4[i];
        *(float4*)&k_lds[row][c4 * 4] = v;
    }
    __syncthreads();

    // q completion: q[mi][ch] = qz[b*3072 + t*64 + ch] + xmT[t>>3]·cwt[col]
    // (t = head*6+mi, col = ((t&7)<<6)|ch — verified remap identities)
    for (int idx = tid; idx < NM * NCH; idx += 256) {
        int mi = idx >> 6, ch = idx & 63;
        int t = head * 6 + mi;
        int mr = t >> 3;
        int col = ((t & 7) << 6) | ch;
        float a = qz[b * 3072 + t * 64 + ch];
        const float4* cw4 = (const float4*)(cwt + col * 64);
        const float4* xv4 = (const float4*)&xmT[mr][0];
        #pragma unroll
        for (int c4 = 0; c4 < 16; ++c4) {
            float4 w = cw4[c4], v = xv4[c4];
            a += w.x*v.x + w.y*v.y + w.z*v.z + w.w*v.w;
        }
        q_lds[mi][ch] = a;
    }
    __syncthreads();

    // dots + exp: 96 threads, thread = k-row u, all 6 m; rotated c4
    if (tid < 96) {
        int u = tid;
        float a[NM] = {0.f,0.f,0.f,0.f,0.f,0.f};
        #pragma unroll
        for (int c4 = 0; c4 < 16; ++c4) {
            int cc = ((c4 + u) & 15) * 4;
            float4 kv = *(const float4*)&k_lds[u][cc];
            #pragma unroll
            for (int mo = 0; mo < NM; ++mo) {
                float4 qv = *(const float4*)&q_lds[mo][cc];
                a[mo] += kv.x*qv.x + kv.y*qv.y + kv.z*qv.z + kv.w*qv.w;
            }
        }
        #pragma unroll
        for (int mo = 0; mo < NM; ++mo) s_lds[mo][u] = __expf(a[mo] * 0.125f);
    }
    __syncthreads();

    int lane = tid & 63, wave = tid >> 6;
    if (wave < 2) {
        // PV: thread (ch, trio) walks all 96 rows; direct po write
        int ch = lane, m0 = wave * 3;
        float a0 = 0.f, a1 = 0.f, a2 = 0.f;
        #pragma unroll
        for (int u0 = 0; u0 < CK; u0 += 4) {
            float4 s0 = *(const float4*)&s_lds[m0 + 0][u0];
            float4 s1 = *(const float4*)&s_lds[m0 + 1][u0];
            float4 s2 = *(const float4*)&s_lds[m0 + 2][u0];
            float kv0 = k_lds[u0 + 0][ch];
            float kv1 = k_lds[u0 + 1][ch];
            float kv2 = k_lds[u0 + 2][ch];
            float kv3 = k_lds[u0 + 3][ch];
            a0 += s0.x*kv0 + s0.y*kv1 + s0.z*kv2 + s0.w*kv3;
            a1 += s1.x*kv0 + s1.y*kv1 + s1.z*kv2 + s1.w*kv3;
            a2 += s2.x*kv0 + s2.y*kv1 + s2.z*kv2 + s2.w*kv3;
        }
        float* pob = po + (size_t)blk * (NM * NCH);
        pob[(m0 + 0) * NCH + ch] = a0;
        pob[(m0 + 1) * NCH + ch] = a1;
        pob[(m0 + 2) * NCH + ch] = a2;
    } else {
        // denominators: waves 2-3, 6 rows in 3 rounds
        #pragma unroll
        for (int rnd = 0; rnd < 3; ++rnd) {
            int mi = rnd * 2 + (wave - 2);
            float v = s_lds[mi][lane] + ((lane < 32) ? s_lds[mi][64 + lane] : 0.f);
            for (int msk = 1; msk < 64; msk <<= 1) v += __shfl_xor(v, msk, 64);
            if (lane == 0) ps[blk * NM + mi] = v;
        }
    }
}

// ============================================================================
// Kernel 3: combine + out-proj + INLINE znew residual (znew buffer deleted).
// grid = NB*NM*4 = 384 blocks; body = R10 proj + xmc/conv per final thread.
// ============================================================================
__global__ __launch_bounds__(256) void proj_kernel(
    const float* __restrict__ z, const float* __restrict__ conv_w,
    const float* __restrict__ conv_b, const float* __restrict__ xmean,
    const float* __restrict__ po, const float* __restrict__ ps,
    const float* __restrict__ wo, const float* __restrict__ bo,
    float* __restrict__ out)
{
    int blk = blockIdx.x;
    int cgrp = blk & 3, bm = blk >> 2;
    int b = bm / NM, m = bm - b * NM;
    int tid = threadIdx.x;
    __shared__ float4 orow4[128];
    __shared__ float4 part4[16][12];
    __shared__ float xmc[NC];

    if (tid < NC) xmc[tid] = xmean[b * 384 + tid * 6 + m];

    if (tid < 128) {
        int h = tid >> 4, c16 = tid & 15;
        int base = (b * NHEADS + h) * NCHUNK;
        const float4* po4 = (const float4*)po;
        float4 n = make_float4(0.f, 0.f, 0.f, 0.f);
        float den = 0.f;
        #pragma unroll
        for (int c = 0; c < NCHUNK; ++c) {
            float4 v = po4[(size_t)(base + c) * 96 + m * 16 + c16];
            n.x += v.x; n.y += v.y; n.z += v.z; n.w += v.w;
            den += ps[(base + c) * NM + m];
        }
        float inv = 1.0f / den;
        n.x *= inv; n.y *= inv; n.z *= inv; n.w *= inv;
        orow4[tid] = n;
    }
    __syncthreads();

    if (tid < 192) {
        int g4 = tid % 12, ks = tid / 12;
        int cb = cgrp * 12 + g4;
        const float4* wo4 = (const float4*)wo;
        const float* orow = (const float*)orow4;
        float4 acc = make_float4(0.f, 0.f, 0.f, 0.f);
        int i0 = ks * 32;
        #pragma unroll 8
        for (int i = i0; i < i0 + 32; ++i) {
            float s = orow[i];
            float4 w = wo4[i * 48 + cb];
            acc.x += s * w.x; acc.y += s * w.y; acc.z += s * w.z; acc.w += s * w.w;
        }
        part4[ks][g4] = acc;
    }
    __syncthreads();

    if (tid < 48) {
        int g4 = tid >> 2, jj = tid & 3;
        float s = 0.f;
        #pragma unroll
        for (int ks = 0; ks < 16; ++ks) s += ((const float*)&part4[ks][g4])[jj];
        int col = cgrp * 48 + tid;
        // inline znew = z + conv_b + conv_w[col,:]·xmc
        float zn = z[bm * ND + col] + conv_b[col];
        const float4* cw4 = (const float4*)(conv_w + col * NC);
        const float4* xv4 = (const float4*)xmc;
        #pragma unroll
        for (int c4 = 0; c4 < 16; ++c4) {
            float4 w = cw4[c4], v = xv4[c4];
            zn += w.x*v.x + w.y*v.y + w.z*v.z + w.w*v.w;
        }
        out[bm * ND + col] = s + bo[col] + zn;
    }
}

extern "C" void kernel_launch(void* const* d_in, const int* in_sizes, int n_in,
                              void* d_out, int out_size, void* d_ws, size_t ws_size,
                              hipStream_t stream) {
    const float* x      = (const float*)d_in[0];
    const float* z      = (const float*)d_in[1];
    const float* conv_w = (const float*)d_in[2];
    const float* conv_b = (const float*)d_in[3];
    const float* wq     = (const float*)d_in[4];
    const float* bq     = (const float*)d_in[5];
    const float* wo     = (const float*)d_in[6];
    const float* bo     = (const float*)d_in[7];
    float* out = (float*)d_out;

    float* ws    = (float*)d_ws;
    float* xmean = ws;               // 16*64*6   = 6144
    float* qz    = ws + 6144;        // 16*48*64  = 49152
    float* cwt   = ws + 55296;       // 512*64    = 32768
    float* po    = ws + 88064;       // 1024*6*64 = 393216
    float* ps    = ws + 481280;      // 1024*6    = 6144

    k1_kernel<<<1856, 256, 0, stream>>>(x, z, conv_w, conv_b, wq, bq,
                                        xmean, qz, cwt);
    fattn_kernel<<<NB*NHEADS*NCHUNK, 256, 0, stream>>>(x, qz, cwt, xmean, po, ps);
    proj_kernel<<<NB*NM*4, 256, 0, stream>>>(z, conv_w, conv_b, xmean,
                                             po, ps, wo, bo, out);
}

// Round 16
// 31.115 us; speedup vs baseline: 7.6334x; 1.4411x over previous
//
#include <hip/hip_runtime.h>

// Problem constants
#define NB 16
#define NC 64
#define NM 6
#define ND 192
#define NHEADS 8
#define NCH 64
#define NINNER 512
#define PLANE 6144             // 64*96 floats per (b,c) plane
#define XB (NC*PLANE)          // 393216 floats of x per batch
#define NKEY 768               // unique keys per head (dup-8 collapses in softmax)
#define NCHUNK 8
#define CK 96                  // keys per chunk (8*96 = 768)

// ---------------- Kernel A: pool ----------------
// grid = NB*NC = 1024 blocks, 256 threads. HBM-bound (25MB at ~5.6TB/s).
__global__ __launch_bounds__(256) void pool_kernel(const float* __restrict__ x,
                                                   float* __restrict__ xmean) {
    int bc = blockIdx.x;
    const float4* p = (const float4*)(x + (size_t)bc * PLANE);
    int tid = threadIdx.x;
    float acc[6] = {0.f,0.f,0.f,0.f,0.f,0.f};
    #pragma unroll
    for (int k = 0; k < 6; ++k) {
        int idx4 = tid + k * 256;
        int hh = idx4 / 24;
        int w4 = idx4 - hh * 24;
        int j = (hh >> 5) * 3 + (w4 >> 3);
        float4 v = p[idx4];
        acc[j] += v.x + v.y + v.z + v.w;
    }
    int lane = tid & 63, wave = tid >> 6;
    #pragma unroll
    for (int j = 0; j < 6; ++j) {
        float v = acc[j];
        for (int off = 32; off > 0; off >>= 1) v += __shfl_down(v, off, 64);
        acc[j] = v;
    }
    __shared__ float part[4][6];
    if (lane == 0) {
        #pragma unroll
        for (int j = 0; j < 6; ++j) part[wave][j] = acc[j];
    }
    __syncthreads();
    if (tid < 6) {
        float s = part[0][tid] + part[1][tid] + part[2][tid] + part[3][tid];
        xmean[bc * 6 + tid] = s * (1.0f / 1024.0f);
    }
}

// ---------------- Kernel B: zq — latency-chain-trimmed ----------------
// grid = NB*NM*8 = 768 blocks, 256 threads. conv_w as float4 (4x ILP);
// q-dot fully unrolled (compiler pipelines the wq L2 loads).
__global__ __launch_bounds__(256) void zq_kernel(const float* __restrict__ z,
                                                 const float* __restrict__ conv_w,
                                                 const float* __restrict__ conv_b,
                                                 const float* __restrict__ wq,
                                                 const float* __restrict__ bq,
                                                 const float* __restrict__ xmean,
                                                 float* __restrict__ znew,
                                                 float* __restrict__ qr) {
    int blk = blockIdx.x;
    int cgrp = blk & 7, bm = blk >> 3;
    int b = bm / NM, m = bm - b * NM;
    int tid = threadIdx.x;
    __shared__ float xm[NC];
    __shared__ float zn[ND];
    __shared__ float qpart[3][64];
    if (tid < NC) xm[tid] = xmean[(b * NC + tid) * NM + m];
    __syncthreads();
    if (tid < ND) {
        float a = conv_b[tid];
        const float4* wr4 = (const float4*)(conv_w + tid * NC);
        #pragma unroll
        for (int c4 = 0; c4 < 16; ++c4) {
            float4 w = wr4[c4];
            a += w.x * xm[c4 * 4 + 0] + w.y * xm[c4 * 4 + 1]
               + w.z * xm[c4 * 4 + 2] + w.w * xm[c4 * 4 + 3];
        }
        float v = z[bm * ND + tid] + a;
        zn[tid] = v;
        if (cgrp == 0) znew[bm * ND + tid] = v;
    }
    __syncthreads();
    int colL = tid & 63, ks = tid >> 6;          // 64 cols x 4-way split-K(48)
    int col = cgrp * 64 + colL;
    float a = (ks == 0) ? bq[col] : 0.f;
    int d0 = ks * 48;
    #pragma unroll
    for (int d = d0; d < d0 + 48; ++d) a += zn[d] * wq[d * NINNER + col];
    if (ks > 0) qpart[ks - 1][colL] = a;
    __syncthreads();
    if (ks == 0) {
        float tot = a + qpart[0][colL] + qpart[1][colL] + qpart[2][colL];
        int t = m * 8 + cgrp;                    // permuted q layout [b][48][64]
        qr[b * (48 * 64) + t * 64 + colL] = tot;
    }
}

// ---------------- Kernel C: fattn v5 — 5 blocks/CU ----------------
// grid = 1024 blocks, 256 threads. LDS 28416B < 32K -> 5 blocks/CU.
// stage -> B1 -> dots(96thr, rotated c4) -> B2 ->
// {waves 0-1: PV direct po write; waves 2-3: denominators}.
__global__ __launch_bounds__(256, 5) void fattn_kernel(const float* __restrict__ x,
                                                       const float* __restrict__ qr,
                                                       float* __restrict__ po,
                                                       float* __restrict__ ps) {
    int blk = blockIdx.x;                    // ((b*8+head)*8+chunk)
    int chunk = blk & 7, bh = blk >> 3;
    int head = bh & 7, b = bh >> 3;
    int tid = threadIdx.x;
    __shared__ float k_lds[CK][NCH];         // 24576 B (pitch 64)
    __shared__ float q_lds[NM][NCH];         //  1536 B
    __shared__ float s_lds[NM][CK];          //  2304 B   (total 28416 B)
    const float* kbase = x + (size_t)b * XB + (size_t)(head * NKEY + chunk * CK) * NCH;

    for (int i = tid; i < NM * NCH; i += 256) {
        int mi = i >> 6, ch = i & 63;
        q_lds[mi][ch] = qr[b * (48 * 64) + (head * NM + mi) * 64 + ch];
    }
    const float4* k4 = (const float4*)kbase;
    #pragma unroll
    for (int r = 0; r < 6; ++r) {
        int i = tid + r * 256;
        int row = i >> 4, c4 = i & 15;
        float4 v = k4[i];
        *(float4*)&k_lds[row][c4 * 4] = v;
    }
    __syncthreads();

    if (tid < 96) {
        int u = tid;
        float a[NM] = {0.f,0.f,0.f,0.f,0.f,0.f};
        #pragma unroll
        for (int c4 = 0; c4 < 16; ++c4) {
            int cc = ((c4 + u) & 15) * 4;
            float4 kv = *(const float4*)&k_lds[u][cc];
            #pragma unroll
            for (int mo = 0; mo < NM; ++mo) {
                float4 qv = *(const float4*)&q_lds[mo][cc];     // broadcast
                a[mo] += kv.x*qv.x + kv.y*qv.y + kv.z*qv.z + kv.w*qv.w;
            }
        }
        #pragma unroll
        for (int mo = 0; mo < NM; ++mo) s_lds[mo][u] = __expf(a[mo] * 0.125f);
    }
    __syncthreads();

    int lane = tid & 63, wave = tid >> 6;

    if (wave < 2) {
        int ch = lane, m0 = wave * 3;
        float a0 = 0.f, a1 = 0.f, a2 = 0.f;
        #pragma unroll
        for (int u0 = 0; u0 < CK; u0 += 4) {
            float4 s0 = *(const float4*)&s_lds[m0 + 0][u0];
            float4 s1 = *(const float4*)&s_lds[m0 + 1][u0];
            float4 s2 = *(const float4*)&s_lds[m0 + 2][u0];
            float kv0 = k_lds[u0 + 0][ch];
            float kv1 = k_lds[u0 + 1][ch];
            float kv2 = k_lds[u0 + 2][ch];
            float kv3 = k_lds[u0 + 3][ch];
            a0 += s0.x*kv0 + s0.y*kv1 + s0.z*kv2 + s0.w*kv3;
            a1 += s1.x*kv0 + s1.y*kv1 + s1.z*kv2 + s1.w*kv3;
            a2 += s2.x*kv0 + s2.y*kv1 + s2.z*kv2 + s2.w*kv3;
        }
        float* pob = po + (size_t)blk * (NM * NCH);
        pob[(m0 + 0) * NCH + ch] = a0;
        pob[(m0 + 1) * NCH + ch] = a1;
        pob[(m0 + 2) * NCH + ch] = a2;
    } else {
        #pragma unroll
        for (int rnd = 0; rnd < 3; ++rnd) {
            int mi = rnd * 2 + (wave - 2);
            float v = s_lds[mi][lane] + ((lane < 32) ? s_lds[mi][64 + lane] : 0.f);
            for (int msk = 1; msk < 64; msk <<= 1) v += __shfl_xor(v, msk, 64);
            if (lane == 0) ps[blk * NM + mi] = v;
        }
    }
}

// ---------------- Kernel D: proj — latency-chain-trimmed ----------------
// grid = NB*NM*4 = 384 blocks. float4 po-combine (den folded per-thread);
// wo-dot as 16-way split-K(32) with float4 wo loads.
__global__ __launch_bounds__(256) void proj_kernel(const float* __restrict__ znew,
                                                   const float* __restrict__ po,
                                                   const float* __restrict__ ps,
                                                   const float* __restrict__ wo,
                                                   const float* __restrict__ bo,
                                                   float* __restrict__ out) {
    int blk = blockIdx.x;
    int cgrp = blk & 3, bm = blk >> 2;
    int b = bm / NM, m = bm - b * NM;
    int tid = threadIdx.x;
    __shared__ float4 orow4[128];
    __shared__ float4 part4[16][12];

    if (tid < 128) {
        int h = tid >> 4, c16 = tid & 15;
        int base = (b * NHEADS + h) * NCHUNK;
        const float4* po4 = (const float4*)po;
        float4 n = make_float4(0.f, 0.f, 0.f, 0.f);
        float den = 0.f;
        #pragma unroll
        for (int c = 0; c < NCHUNK; ++c) {
            float4 v = po4[(size_t)(base + c) * 96 + m * 16 + c16];
            n.x += v.x; n.y += v.y; n.z += v.z; n.w += v.w;
            den += ps[(base + c) * NM + m];
        }
        float inv = 1.0f / den;
        n.x *= inv; n.y *= inv; n.z *= inv; n.w *= inv;
        orow4[tid] = n;
    }
    __syncthreads();

    if (tid < 192) {
        int g4 = tid % 12, ks = tid / 12;
        int cb = cgrp * 12 + g4;
        const float4* wo4 = (const float4*)wo;
        const float* orow = (const float*)orow4;
        float4 acc = make_float4(0.f, 0.f, 0.f, 0.f);
        int i0 = ks * 32;
        #pragma unroll 8
        for (int i = i0; i < i0 + 32; ++i) {
            float s = orow[i];
            float4 w = wo4[i * 48 + cb];
            acc.x += s * w.x; acc.y += s * w.y; acc.z += s * w.z; acc.w += s * w.w;
        }
        part4[ks][g4] = acc;
    }
    __syncthreads();

    if (tid < 48) {
        int g4 = tid >> 2, j = tid & 3;
        float s = 0.f;
        #pragma unroll
        for (int ks = 0; ks < 16; ++ks) s += ((const float*)&part4[ks][g4])[j];
        int col = cgrp * 48 + tid;
        out[bm * ND + col] = s + bo[col] + znew[bm * ND + col];
    }
}

extern "C" void kernel_launch(void* const* d_in, const int* in_sizes, int n_in,
                              void* d_out, int out_size, void* d_ws, size_t ws_size,
                              hipStream_t stream) {
    const float* x      = (const float*)d_in[0];
    const float* z      = (const float*)d_in[1];
    const float* conv_w = (const float*)d_in[2];
    const float* conv_b = (const float*)d_in[3];
    const float* wq     = (const float*)d_in[4];
    const float* bq     = (const float*)d_in[5];
    const float* wo     = (const float*)d_in[6];
    const float* bo     = (const float*)d_in[7];
    float* out = (float*)d_out;

    float* ws    = (float*)d_ws;
    float* xmean = ws;              // 16*64*6          = 6144
    float* znew  = ws + 6144;       // 16*6*192         = 18432
    float* qr    = ws + 24576;      // 16*48*64         = 49152
    float* po    = ws + 73728;      // 1024*6*64        = 393216
    float* ps    = ws + 466944;     // 1024*6           = 6144

    pool_kernel<<<NB*NC, 256, 0, stream>>>(x, xmean);
    zq_kernel<<<NB*NM*8, 256, 0, stream>>>(z, conv_w, conv_b, wq, bq, xmean, znew, qr);
    fattn_kernel<<<NB*NHEADS*NCHUNK, 256, 0, stream>>>(x, qr, po, ps);
    proj_kernel<<<NB*NM*4, 256, 0, stream>>>(znew, po, ps, wo, bo, out);
}